// Round 6
// baseline (698.099 us; speedup 1.0000x reference)
//
#include <hip/hip_runtime.h>
#include <hip/hip_bf16.h>

#define NN 6607
#define HH 64
#define TT 3
#define EE 1000000

typedef __attribute__((ext_vector_type(8))) short bf16x8;
typedef __attribute__((ext_vector_type(4))) short short4v;
typedef __attribute__((ext_vector_type(4))) float f32x4;
typedef __attribute__((ext_vector_type(2))) float f32x2;
typedef __attribute__((ext_vector_type(4))) int i32x4;

// LDS-only barrier: orders LDS ops across the block WITHOUT draining vmem stores
// (global stores consume register data; LDS double-buffer only needs lgkm ordering).
#define LGKM_BARRIER() do { \
    __builtin_amdgcn_sched_barrier(0); \
    asm volatile("s_waitcnt lgkmcnt(0)" ::: "memory"); \
    __builtin_amdgcn_s_barrier(); \
    __builtin_amdgcn_sched_barrier(0); \
} while (0)

// ---------------- fused prep: zero(degI+cursor) + Wrec->bf16 + x_init copy ----------------

__global__ void prep_kernel(const float* __restrict__ wrec, short* __restrict__ wrecb,
                            const float* __restrict__ emb, float* __restrict__ o_xinit,
                            int* __restrict__ zero_base) {
    int i = blockIdx.x * 256 + threadIdx.x;
    if (i < 9912) ((i32x4*)zero_base)[i] = (i32x4){0, 0, 0, 0};
    if (i < 105712) ((f32x4*)o_xinit)[i] = ((const f32x4*)emb)[i];
    if (i < 317136) {
        f32x4 v = ((const f32x4*)wrec)[i];
        short4v s;
        s[0] = (short)__bfloat16_as_ushort(__float2bfloat16(v[0]));
        s[1] = (short)__bfloat16_as_ushort(__float2bfloat16(v[1]));
        s[2] = (short)__bfloat16_as_ushort(__float2bfloat16(v[2]));
        s[3] = (short)__bfloat16_as_ushort(__float2bfloat16(v[3]));
        ((short4v*)wrecb)[i] = s;
    }
}

// ---------------- CSR build ----------------

__global__ void hist_kernel(const int* __restrict__ ei, int* __restrict__ degI) {
    int e = blockIdx.x * 256 + threadIdx.x;
    int t = blockIdx.y;
    if (e >= EE) return;
    int dst = ei[t * 2 * EE + EE + e];
    atomicAdd(&degI[t * NN + dst], 1);
}

// Barrier-free single-wave scan per type: 104 iterations of shfl_up inclusive scan.
__global__ void scan_kernel(const int* __restrict__ degI, int* __restrict__ rowptr) {
    int t = blockIdx.x;
    int lane = threadIdx.x;  // 64 threads
    const int* d = degI + t * NN;
    int* rp = rowptr + t * (NN + 1);
    int carry = 0;
    for (int base = 0; base < NN; base += 64) {
        int i = base + lane;
        int v = (i < NN) ? d[i] : 0;
        int s = v;
        #pragma unroll
        for (int off = 1; off < 64; off <<= 1) {
            int u = __shfl_up(s, off, 64);
            if (lane >= off) s += u;
        }
        if (i < NN) rp[i] = carry + s - v;  // exclusive
        carry += __shfl(s, 63, 64);
    }
    if (lane == 0) rp[NN] = carry;  // == EE
}

__global__ void fill_kernel(const int* __restrict__ ei, const int* __restrict__ rowptr,
                            int* __restrict__ cursor, int* __restrict__ csr) {
    int e = blockIdx.x * 256 + threadIdx.x;
    int t = blockIdx.y;
    if (e >= EE) return;
    int src = ei[t * 2 * EE + e];
    int dst = ei[t * 2 * EE + EE + e];
    int pos = atomicAdd(&cursor[t * NN + dst], 1);
    csr[t * EE + rowptr[t * (NN + 1) + dst] + pos] = src;
}

// ---------------- SAGE layer ----------------
// 4 waves/block, wave owns node i. Gather: 32-lane float2 form — each instruction
// gathers TWO edge rows (512B); edge indices via aligned int2 (2 loads per 8 edges).

template <int LAYER>
__global__ void sage_kernel(const float* __restrict__ x_all,
                            const int* __restrict__ rowptr, const int* __restrict__ csr,
                            const float* __restrict__ W_l, const float* __restrict__ b_l,
                            const float* __restrict__ W_r,
                            float* __restrict__ y, __hip_bfloat16* __restrict__ yb) {
    int t = blockIdx.y;
    __shared__ float wl[64][68];
    __shared__ float wr[64][68];
    __shared__ float mean_s[4][64];
    __shared__ float xi_s[4][64];
    const f32x4* Wl4 = (const f32x4*)(W_l + t * 4096);
    const f32x4* Wr4 = (const f32x4*)(W_r + t * 4096);
    for (int cc = threadIdx.x; cc < 1024; cc += 256) {
        int h = cc >> 4, k = (cc & 15) << 2;
        *(f32x4*)&wl[h][k] = Wl4[cc];
        *(f32x4*)&wr[h][k] = Wr4[cc];
    }
    __syncthreads();

    int lane = threadIdx.x & 63;
    int widx = threadIdx.x >> 6;
    int i = blockIdx.x * 4 + widx;
    if (i >= NN) return;

    const float* x = x_all + (LAYER == 2 ? (size_t)t * NN * HH : 0);
    const f32x2* x2 = (const f32x2*)x;   // row stride 32 f32x2
    int rp0 = rowptr[t * (NN + 1) + i];
    int rp1 = rowptr[t * (NN + 1) + i + 1];
    const int* cs = csr + t * EE;

    int h2 = lane >> 5;   // half index
    int c = lane & 31;    // channel pair: ch 2c, 2c+1

    f32x2 ac0 = {0.f, 0.f}, ac1 = {0.f, 0.f}, ac2 = {0.f, 0.f}, ac3 = {0.f, 0.f};
    int e = rp0;
    // peel to even e for aligned int2 index loads
    if ((e & 1) && e < rp1) {
        if (h2 == 0) ac0 += x2[(size_t)cs[e] * 32 + c];
        ++e;
    }
    for (; e + 8 <= rp1; e += 8) {
        const int2* q = (const int2*)(cs + e) + 2 * h2;
        int2 p0 = q[0], p1 = q[1];
        ac0 += x2[(size_t)p0.x * 32 + c];
        ac1 += x2[(size_t)p0.y * 32 + c];
        ac2 += x2[(size_t)p1.x * 32 + c];
        ac3 += x2[(size_t)p1.y * 32 + c];
    }
    f32x2 accT = (ac0 + ac1) + (ac2 + ac3);
    if (h2 == 0) {
        for (; e < rp1; ++e) accT += x2[(size_t)cs[e] * 32 + c];
    }
    // combine halves
    accT[0] += __shfl_xor(accT[0], 32, 64);
    accT[1] += __shfl_xor(accT[1], 32, 64);

    int d = rp1 - rp0;
    float inv = 1.f / (float)(d > 1 ? d : 1);
    f32x2 mean2 = accT * inv;
    f32x2 xi2 = x2[(size_t)i * 32 + c];

    if (h2 == 0) {
        *(f32x2*)&mean_s[widx][2 * c] = mean2;
        *(f32x2*)&xi_s[widx][2 * c] = xi2;
    }
    // same-wave LDS write->read: compiler inserts lgkmcnt wait

    float out = b_l[t * 64 + lane];
    #pragma unroll 4
    for (int k0 = 0; k0 < 64; k0 += 4) {
        f32x4 m4 = *(const f32x4*)&mean_s[widx][k0];
        f32x4 x4 = *(const f32x4*)&xi_s[widx][k0];
        f32x4 l4 = *(const f32x4*)&wl[lane][k0];
        f32x4 r4 = *(const f32x4*)&wr[lane][k0];
        out += m4[0] * l4[0] + m4[1] * l4[1] + m4[2] * l4[2] + m4[3] * l4[3];
        out += x4[0] * r4[0] + x4[1] * r4[1] + x4[2] * r4[2] + x4[3] * r4[3];
    }
    out = fmaxf(out, 0.f);
    y[(size_t)t * NN * HH + i * 64 + lane] = out;
    if (LAYER == 2) yb[(size_t)t * NN * HH + i * 64 + lane] = __float2bfloat16(out);
}

// ---------------- reconstruction: recon[t] = h2[t] @ Wrec[t]^T + brec[t] ----------------
// 16-row strip x full width per block, 26 chunks of 256 cols, double-buffered LDS.
// Stores are NONTEMPORAL (write-only 524MB must not thrash L2 where B lives) and the
// inter-chunk barrier waits lgkmcnt only (stores stay in flight across chunks).

__global__ void recon_kernel(const short* __restrict__ h2b, const short* __restrict__ wrecb,
                             const float* __restrict__ brec, float* __restrict__ out) {
    constexpr int NI = (NN + 15) / 16;   // 413 strips
    constexpr int NCH = 26;              // 256-col chunks
    __shared__ float buf[2][16][260];

    int bid = blockIdx.x;
    int t = bid / NI;
    int it = bid % NI;
    int i0 = it * 16;

    int tid = threadIdx.x;
    int lane = tid & 63;
    int w = tid >> 6;
    int r = lane & 15;
    int kb = (lane >> 4) * 8;
    int rbase = (lane >> 4) * 4;

    const short* A = h2b + (size_t)t * NN * HH;
    const short* B = wrecb + (size_t)t * NN * HH;
    const float* br = brec + t * NN;
    size_t obase = (size_t)t * NN * NN;

    bf16x8 a0 = *(const bf16x8*)(A + (size_t)(i0 + r) * 64 + kb);
    bf16x8 a1 = *(const bf16x8*)(A + (size_t)(i0 + r) * 64 + kb + 32);

    int srow_base = tid >> 6;        // rows 0..3 (+4 per pass)
    int scol = (tid & 63) << 2;      // 0..252

    auto compute = [&](int chunk, int bi) {
        int jbase = chunk * 256 + w * 64;
        #pragma unroll
        for (int jt = 0; jt < 4; ++jt) {
            int j0 = jbase + jt * 16;
            bf16x8 b0 = *(const bf16x8*)(B + (size_t)(j0 + r) * 64 + kb);
            bf16x8 b1 = *(const bf16x8*)(B + (size_t)(j0 + r) * 64 + kb + 32);
            f32x4 acc = {0.f, 0.f, 0.f, 0.f};
            acc = __builtin_amdgcn_mfma_f32_16x16x32_bf16(a0, b0, acc, 0, 0, 0);
            acc = __builtin_amdgcn_mfma_f32_16x16x32_bf16(a1, b1, acc, 0, 0, 0);
            int jloc = w * 64 + jt * 16 + r;
            #pragma unroll
            for (int q = 0; q < 4; ++q) buf[bi][rbase + q][jloc] = acc[q];
        }
    };

    auto store = [&](int chunk, int bi) {
        int colg = chunk * 256 + scol;
        if (colg >= NN) return;
        bool full4 = (colg + 4 <= NN);
        float bx = br[colg];
        float by = full4 ? br[colg + 1] : ((colg + 1 < NN) ? br[colg + 1] : 0.f);
        float bz = full4 ? br[colg + 2] : ((colg + 2 < NN) ? br[colg + 2] : 0.f);
        float bw = full4 ? br[colg + 3] : 0.f;
        #pragma unroll
        for (int p = 0; p < 4; ++p) {
            int rloc = p * 4 + srow_base;
            int row = i0 + rloc;
            if (row >= NN) continue;
            f32x4 v = *(const f32x4*)&buf[bi][rloc][scol];
            float* pp = out + obase + (size_t)row * NN + colg;
            if (full4) {
                f32x4 wv = {v[0] + bx, v[1] + by, v[2] + bz, v[3] + bw};
                __builtin_nontemporal_store(wv, (f32x4*)pp);
            } else {
                __builtin_nontemporal_store(v[0] + bx, pp);
                if (colg + 1 < NN) __builtin_nontemporal_store(v[1] + by, pp + 1);
                if (colg + 2 < NN) __builtin_nontemporal_store(v[2] + bz, pp + 2);
            }
        }
    };

    compute(0, 0);
    LGKM_BARRIER();
    for (int c = 1; c < NCH; ++c) {
        store(c - 1, (c - 1) & 1);   // nt stores drain under next chunk's compute
        compute(c, c & 1);
        LGKM_BARRIER();
    }
    store(NCH - 1, (NCH - 1) & 1);
}

// ---------------- launch ----------------

extern "C" void kernel_launch(void* const* d_in, const int* in_sizes, int n_in,
                              void* d_out, int out_size, void* d_ws, size_t ws_size,
                              hipStream_t stream) {
    const float* emb  = (const float*)d_in[0];
    const int*   ei   = (const int*)d_in[1];
    const float* W1l  = (const float*)d_in[2];
    const float* b1   = (const float*)d_in[3];
    const float* W1r  = (const float*)d_in[4];
    const float* W2l  = (const float*)d_in[5];
    const float* b2   = (const float*)d_in[6];
    const float* W2r  = (const float*)d_in[7];
    const float* Wrec = (const float*)d_in[8];
    const float* brec = (const float*)d_in[9];

    char* ws = (char*)d_ws;
    int*   degI   = (int*)(ws + 0);                       // 79284 -> pad 79296
    int*   cursor = (int*)(ws + 79296);                   // 79284 -> pad 79296 (zeroed with degI)
    int*   rowptr = (int*)(ws + 158592);                  // 79296 (fully overwritten by scan)
    int*   csr    = (int*)(ws + 237888);                  // 12000000
    float* h1     = (float*)(ws + 12237888);              // 5074176
    short* h2b    = (short*)(ws + 17312064);              // (3*6607*64+4096)*2 = 2545280
    short* wrecb  = (short*)(ws + 19857344);              // 2545280 -> end 22402624

    float* o_emb   = (float*)d_out;                        // [T][N][H]
    float* o_recon = o_emb + (size_t)TT * NN * HH;         // [T][N][N]
    float* o_xinit = o_recon + (size_t)TT * NN * NN;       // [N][H]

    prep_kernel<<<(317136 + 255) / 256, 256, 0, stream>>>(Wrec, wrecb, emb, o_xinit, (int*)ws);

    dim3 egrid((EE + 255) / 256, TT);
    hist_kernel<<<egrid, 256, 0, stream>>>(ei, degI);
    scan_kernel<<<TT, 64, 0, stream>>>(degI, rowptr);
    fill_kernel<<<egrid, 256, 0, stream>>>(ei, rowptr, cursor, csr);

    dim3 sgrid((NN + 3) / 4, TT);
    sage_kernel<1><<<sgrid, 256, 0, stream>>>(emb, rowptr, csr, W1l, b1, W1r, h1, nullptr);
    sage_kernel<2><<<sgrid, 256, 0, stream>>>(h1, rowptr, csr, W2l, b2, W2r, o_emb,
                                              (__hip_bfloat16*)h2b);

    constexpr int NI = (NN + 15) / 16;   // 413
    int rblocks = NI * TT;               // 1239
    recon_kernel<<<rblocks, 256, 0, stream>>>(h2b, wrecb, brec, o_recon);
}

// Round 7
// 673.129 us; speedup vs baseline: 1.0371x; 1.0371x over previous
//
#include <hip/hip_runtime.h>
#include <hip/hip_bf16.h>

#define NN 6607
#define HH 64
#define TT 3
#define EE 1000000

typedef __attribute__((ext_vector_type(8))) short bf16x8;
typedef __attribute__((ext_vector_type(4))) short short4v;
typedef __attribute__((ext_vector_type(4))) float f32x4;
typedef __attribute__((ext_vector_type(2))) float f32x2;
typedef __attribute__((ext_vector_type(4))) int i32x4;

// LDS-only barrier: orders LDS ops across the block WITHOUT draining vmem
// (stores stay in flight across chunks). sched_barrier fences hoisting (rule #18).
#define LGKM_BARRIER() do { \
    __builtin_amdgcn_sched_barrier(0); \
    asm volatile("s_waitcnt lgkmcnt(0)" ::: "memory"); \
    __builtin_amdgcn_s_barrier(); \
    __builtin_amdgcn_sched_barrier(0); \
} while (0)

// ---------------- fused prep: zero(degI+cursor) + Wrec->bf16 + x_init copy ----------------

__global__ void prep_kernel(const float* __restrict__ wrec, short* __restrict__ wrecb,
                            const float* __restrict__ emb, float* __restrict__ o_xinit,
                            int* __restrict__ zero_base) {
    int i = blockIdx.x * 256 + threadIdx.x;
    if (i < 9912) ((i32x4*)zero_base)[i] = (i32x4){0, 0, 0, 0};
    if (i < 105712) ((f32x4*)o_xinit)[i] = ((const f32x4*)emb)[i];
    if (i < 317136) {
        f32x4 v = ((const f32x4*)wrec)[i];
        short4v s;
        s[0] = (short)__bfloat16_as_ushort(__float2bfloat16(v[0]));
        s[1] = (short)__bfloat16_as_ushort(__float2bfloat16(v[1]));
        s[2] = (short)__bfloat16_as_ushort(__float2bfloat16(v[2]));
        s[3] = (short)__bfloat16_as_ushort(__float2bfloat16(v[3]));
        ((short4v*)wrecb)[i] = s;
    }
}

// ---------------- CSR build ----------------

__global__ void hist_kernel(const int* __restrict__ ei, int* __restrict__ degI) {
    int e = blockIdx.x * 256 + threadIdx.x;
    int t = blockIdx.y;
    if (e >= EE) return;
    int dst = ei[t * 2 * EE + EE + e];
    atomicAdd(&degI[t * NN + dst], 1);
}

__global__ void scan_kernel(const int* __restrict__ degI, int* __restrict__ rowptr) {
    int t = blockIdx.x;
    int lane = threadIdx.x;  // 64 threads
    const int* d = degI + t * NN;
    int* rp = rowptr + t * (NN + 1);
    int carry = 0;
    for (int base = 0; base < NN; base += 64) {
        int i = base + lane;
        int v = (i < NN) ? d[i] : 0;
        int s = v;
        #pragma unroll
        for (int off = 1; off < 64; off <<= 1) {
            int u = __shfl_up(s, off, 64);
            if (lane >= off) s += u;
        }
        if (i < NN) rp[i] = carry + s - v;  // exclusive
        carry += __shfl(s, 63, 64);
    }
    if (lane == 0) rp[NN] = carry;  // == EE
}

__global__ void fill_kernel(const int* __restrict__ ei, const int* __restrict__ rowptr,
                            int* __restrict__ cursor, int* __restrict__ csr) {
    int e = blockIdx.x * 256 + threadIdx.x;
    int t = blockIdx.y;
    if (e >= EE) return;
    int src = ei[t * 2 * EE + e];
    int dst = ei[t * 2 * EE + EE + e];
    int pos = atomicAdd(&cursor[t * NN + dst], 1);
    csr[t * EE + rowptr[t * (NN + 1) + dst] + pos] = src;
}

// ---------------- SAGE layer ----------------

template <int LAYER>
__global__ void sage_kernel(const float* __restrict__ x_all,
                            const int* __restrict__ rowptr, const int* __restrict__ csr,
                            const float* __restrict__ W_l, const float* __restrict__ b_l,
                            const float* __restrict__ W_r,
                            float* __restrict__ y, __hip_bfloat16* __restrict__ yb) {
    int t = blockIdx.y;
    __shared__ float wl[64][68];
    __shared__ float wr[64][68];
    __shared__ float mean_s[4][64];
    __shared__ float xi_s[4][64];
    const f32x4* Wl4 = (const f32x4*)(W_l + t * 4096);
    const f32x4* Wr4 = (const f32x4*)(W_r + t * 4096);
    for (int cc = threadIdx.x; cc < 1024; cc += 256) {
        int h = cc >> 4, k = (cc & 15) << 2;
        *(f32x4*)&wl[h][k] = Wl4[cc];
        *(f32x4*)&wr[h][k] = Wr4[cc];
    }
    __syncthreads();

    int lane = threadIdx.x & 63;
    int widx = threadIdx.x >> 6;
    int i = blockIdx.x * 4 + widx;
    if (i >= NN) return;

    const float* x = x_all + (LAYER == 2 ? (size_t)t * NN * HH : 0);
    const f32x2* x2 = (const f32x2*)x;
    int rp0 = rowptr[t * (NN + 1) + i];
    int rp1 = rowptr[t * (NN + 1) + i + 1];
    const int* cs = csr + t * EE;

    int h2 = lane >> 5;
    int c = lane & 31;

    f32x2 ac0 = {0.f, 0.f}, ac1 = {0.f, 0.f}, ac2 = {0.f, 0.f}, ac3 = {0.f, 0.f};
    int e = rp0;
    if ((e & 1) && e < rp1) {
        if (h2 == 0) ac0 += x2[(size_t)cs[e] * 32 + c];
        ++e;
    }
    for (; e + 8 <= rp1; e += 8) {
        const int2* q = (const int2*)(cs + e) + 2 * h2;
        int2 p0 = q[0], p1 = q[1];
        ac0 += x2[(size_t)p0.x * 32 + c];
        ac1 += x2[(size_t)p0.y * 32 + c];
        ac2 += x2[(size_t)p1.x * 32 + c];
        ac3 += x2[(size_t)p1.y * 32 + c];
    }
    f32x2 accT = (ac0 + ac1) + (ac2 + ac3);
    if (h2 == 0) {
        for (; e < rp1; ++e) accT += x2[(size_t)cs[e] * 32 + c];
    }
    accT[0] += __shfl_xor(accT[0], 32, 64);
    accT[1] += __shfl_xor(accT[1], 32, 64);

    int d = rp1 - rp0;
    float inv = 1.f / (float)(d > 1 ? d : 1);
    f32x2 mean2 = accT * inv;
    f32x2 xi2 = x2[(size_t)i * 32 + c];

    if (h2 == 0) {
        *(f32x2*)&mean_s[widx][2 * c] = mean2;
        *(f32x2*)&xi_s[widx][2 * c] = xi2;
    }

    float out = b_l[t * 64 + lane];
    #pragma unroll 4
    for (int k0 = 0; k0 < 64; k0 += 4) {
        f32x4 m4 = *(const f32x4*)&mean_s[widx][k0];
        f32x4 x4 = *(const f32x4*)&xi_s[widx][k0];
        f32x4 l4 = *(const f32x4*)&wl[lane][k0];
        f32x4 r4 = *(const f32x4*)&wr[lane][k0];
        out += m4[0] * l4[0] + m4[1] * l4[1] + m4[2] * l4[2] + m4[3] * l4[3];
        out += x4[0] * r4[0] + x4[1] * r4[1] + x4[2] * r4[2] + x4[3] * r4[3];
    }
    out = fmaxf(out, 0.f);
    y[(size_t)t * NN * HH + i * 64 + lane] = out;
    if (LAYER == 2) yb[(size_t)t * NN * HH + i * 64 + lane] = __float2bfloat16(out);
}

// ---------------- reconstruction: recon[t] = h2[t] @ Wrec[t]^T + brec[t] ----------------
// vmcnt-decoupled pipeline: per chunk, issue B+bias loads FIRST, then store(c-1)
// (pure LDS-read + nt-store, zero vmem loads), then MFMA (its s_waitcnt only counts
// the 16 younger stores -> stores never drain inside the loop). Bias folded into
// MFMA accumulator init (acc[q] all share col j0+r). One lgkm-only barrier per chunk.

__global__ void recon_kernel(const short* __restrict__ h2b, const short* __restrict__ wrecb,
                             const float* __restrict__ brec, float* __restrict__ out) {
    constexpr int NI = (NN + 15) / 16;   // 413 strips
    constexpr int NCH = 26;              // 256-col chunks
    __shared__ float buf[2][16][260];

    int bid = blockIdx.x;
    int t = bid / NI;
    int it = bid % NI;
    int i0 = it * 16;

    int tid = threadIdx.x;
    int lane = tid & 63;
    int w = tid >> 6;
    int r = lane & 15;
    int kb = (lane >> 4) * 8;
    int rbase = (lane >> 4) * 4;

    const short* A = h2b + (size_t)t * NN * HH;
    const short* B = wrecb + (size_t)t * NN * HH;
    const float* br = brec + t * NN;
    size_t obase = (size_t)t * NN * NN;

    bf16x8 a0 = *(const bf16x8*)(A + (size_t)(i0 + r) * 64 + kb);
    bf16x8 a1 = *(const bf16x8*)(A + (size_t)(i0 + r) * 64 + kb + 32);

    int scol = lane << 2;            // 0..252 (store col offset within chunk)

    bf16x8 Breg[8];
    float biasreg[4];

    auto loadB = [&](int chunk) {
        int jbase = chunk * 256 + w * 64;
        #pragma unroll
        for (int jt = 0; jt < 4; ++jt) {
            int j0 = jbase + jt * 16;
            Breg[2 * jt]     = *(const bf16x8*)(B + (size_t)(j0 + r) * 64 + kb);
            Breg[2 * jt + 1] = *(const bf16x8*)(B + (size_t)(j0 + r) * 64 + kb + 32);
            int col = j0 + r;
            col = col < NN ? col : NN - 1;   // clamp (brec has no pad)
            biasreg[jt] = br[col];
        }
    };

    auto mfma_phase = [&](int bi) {
        #pragma unroll
        for (int jt = 0; jt < 4; ++jt) {
            float bb = biasreg[jt];
            f32x4 acc = {bb, bb, bb, bb};
            acc = __builtin_amdgcn_mfma_f32_16x16x32_bf16(a0, Breg[2 * jt], acc, 0, 0, 0);
            acc = __builtin_amdgcn_mfma_f32_16x16x32_bf16(a1, Breg[2 * jt + 1], acc, 0, 0, 0);
            int jloc = w * 64 + jt * 16 + r;
            #pragma unroll
            for (int q = 0; q < 4; ++q) buf[bi][rbase + q][jloc] = acc[q];
        }
    };

    auto store_phase = [&](int chunk, int bi) {
        int colg = chunk * 256 + scol;
        if (colg >= NN) return;
        bool full4 = (colg + 4 <= NN);
        #pragma unroll
        for (int p = 0; p < 4; ++p) {
            int rloc = p * 4 + w;
            int row = i0 + rloc;
            if (row >= NN) continue;
            f32x4 v = *(const f32x4*)&buf[bi][rloc][scol];   // bias already added
            float* pp = out + obase + (size_t)row * NN + colg;
            if (full4) {
                __builtin_nontemporal_store(v, (f32x4*)pp);
            } else {
                __builtin_nontemporal_store(v[0], pp);
                if (colg + 1 < NN) __builtin_nontemporal_store(v[1], pp + 1);
                if (colg + 2 < NN) __builtin_nontemporal_store(v[2], pp + 2);
            }
        }
    };

    loadB(0);
    mfma_phase(0);
    LGKM_BARRIER();
    for (int c = 1; c < NCH; ++c) {
        loadB(c);                       // 12 vmem loads issued FIRST
        store_phase(c - 1, (c - 1) & 1);// 16 stores (younger than loads)
        mfma_phase(c & 1);              // waitcnt counts only the stores -> no drain
        LGKM_BARRIER();
    }
    store_phase(NCH - 1, (NCH - 1) & 1);
}

// ---------------- launch ----------------

extern "C" void kernel_launch(void* const* d_in, const int* in_sizes, int n_in,
                              void* d_out, int out_size, void* d_ws, size_t ws_size,
                              hipStream_t stream) {
    const float* emb  = (const float*)d_in[0];
    const int*   ei   = (const int*)d_in[1];
    const float* W1l  = (const float*)d_in[2];
    const float* b1   = (const float*)d_in[3];
    const float* W1r  = (const float*)d_in[4];
    const float* W2l  = (const float*)d_in[5];
    const float* b2   = (const float*)d_in[6];
    const float* W2r  = (const float*)d_in[7];
    const float* Wrec = (const float*)d_in[8];
    const float* brec = (const float*)d_in[9];

    char* ws = (char*)d_ws;
    int*   degI   = (int*)(ws + 0);                       // 79284 -> pad 79296
    int*   cursor = (int*)(ws + 79296);                   // 79284 -> pad 79296 (zeroed with degI)
    int*   rowptr = (int*)(ws + 158592);                  // 79296 (fully overwritten by scan)
    int*   csr    = (int*)(ws + 237888);                  // 12000000
    float* h1     = (float*)(ws + 12237888);              // 5074176
    short* h2b    = (short*)(ws + 17312064);              // (3*6607*64+4096)*2 = 2545280
    short* wrecb  = (short*)(ws + 19857344);              // 2545280 -> end 22402624

    float* o_emb   = (float*)d_out;                        // [T][N][H]
    float* o_recon = o_emb + (size_t)TT * NN * HH;         // [T][N][N]
    float* o_xinit = o_recon + (size_t)TT * NN * NN;       // [N][H]

    prep_kernel<<<(317136 + 255) / 256, 256, 0, stream>>>(Wrec, wrecb, emb, o_xinit, (int*)ws);

    dim3 egrid((EE + 255) / 256, TT);
    hist_kernel<<<egrid, 256, 0, stream>>>(ei, degI);
    scan_kernel<<<TT, 64, 0, stream>>>(degI, rowptr);
    fill_kernel<<<egrid, 256, 0, stream>>>(ei, rowptr, cursor, csr);

    dim3 sgrid((NN + 3) / 4, TT);
    sage_kernel<1><<<sgrid, 256, 0, stream>>>(emb, rowptr, csr, W1l, b1, W1r, h1, nullptr);
    sage_kernel<2><<<sgrid, 256, 0, stream>>>(h1, rowptr, csr, W2l, b2, W2r, o_emb,
                                              (__hip_bfloat16*)h2b);

    constexpr int NI = (NN + 15) / 16;   // 413
    int rblocks = NI * TT;               // 1239
    recon_kernel<<<rblocks, 256, 0, stream>>>(h2b, wrecb, brec, o_recon);
}